// Round 6
// baseline (209.214 us; speedup 1.0000x reference)
//
#include <hip/hip_runtime.h>
#include <math.h>

#define IN_DIM   128
#define OUT_DIM  128
#define FEAT_DIM 64
#define NB       64     // nodes per k_linear block
#define SCH      256    // scan chunk size

// ---------------------------------------------------------------------------
// z = h @ W_fc ; dz = feat @ W_dst.  256 threads/block, 64 nodes/block.
// Grid = 2*nbz blocks: first nbz do z, rest do dz (doubles TLP vs fused).
// Thread = (col-group c: 4 cols) x (node-group j0: 8 consecutive nodes).
// ---------------------------------------------------------------------------
__global__ __launch_bounds__(256) void k_linear(
        const float* __restrict__ h, const float* __restrict__ feat,
        const float* __restrict__ Wfc, const float* __restrict__ Wdst,
        float* __restrict__ z, float* __restrict__ dz, int N, int nbz) {
    int t  = threadIdx.x;        // 0..255
    int c  = t & 31;             // cols 4c..4c+3
    int j0 = t >> 5;             // 0..7 -> nodes n0 + 8*j0 + jj
    int b  = blockIdx.x;
    bool do_z = (b < nbz);
    int n0 = (do_z ? b : b - nbz) * NB;

    __shared__ float4 s[NB * 32];   // 32 KB

    float4 acc[8];
#pragma unroll
    for (int jj = 0; jj < 8; ++jj) acc[jj] = make_float4(0.f, 0.f, 0.f, 0.f);

    if (do_z) {
        for (int i = t; i < NB * 32; i += 256) {
            int row = i >> 5, col = i & 31;
            int n = min(n0 + row, N - 1);
            s[i] = ((const float4*)(h + (size_t)n * IN_DIM))[col];
        }
        __syncthreads();

        const float4* Wf4 = (const float4*)Wfc;
#pragma unroll 2
        for (int k4 = 0; k4 < IN_DIM / 4; ++k4) {
            float4 w0 = Wf4[(size_t)(4 * k4 + 0) * 32 + c];
            float4 w1 = Wf4[(size_t)(4 * k4 + 1) * 32 + c];
            float4 w2 = Wf4[(size_t)(4 * k4 + 2) * 32 + c];
            float4 w3 = Wf4[(size_t)(4 * k4 + 3) * 32 + c];
#pragma unroll
            for (int jj = 0; jj < 8; ++jj) {
                float4 hv = s[(j0 * 8 + jj) * 32 + k4];
                acc[jj].x += hv.x * w0.x + hv.y * w1.x + hv.z * w2.x + hv.w * w3.x;
                acc[jj].y += hv.x * w0.y + hv.y * w1.y + hv.z * w2.y + hv.w * w3.y;
                acc[jj].z += hv.x * w0.z + hv.y * w1.z + hv.z * w2.z + hv.w * w3.z;
                acc[jj].w += hv.x * w0.w + hv.y * w1.w + hv.z * w2.w + hv.w * w3.w;
            }
        }
#pragma unroll
        for (int jj = 0; jj < 8; ++jj) {
            int n = n0 + j0 * 8 + jj;
            if (n < N) ((float4*)(z + (size_t)n * OUT_DIM))[c] = acc[jj];
        }
    } else {
        for (int i = t; i < NB * 16; i += 256) {
            int row = i >> 4, col = i & 15;
            int n = min(n0 + row, N - 1);
            s[i] = ((const float4*)(feat + (size_t)n * FEAT_DIM))[col];
        }
        __syncthreads();

        const float4* Wd4 = (const float4*)Wdst;
#pragma unroll 2
        for (int k4 = 0; k4 < FEAT_DIM / 4; ++k4) {
            float4 w0 = Wd4[(size_t)(4 * k4 + 0) * 32 + c];
            float4 w1 = Wd4[(size_t)(4 * k4 + 1) * 32 + c];
            float4 w2 = Wd4[(size_t)(4 * k4 + 2) * 32 + c];
            float4 w3 = Wd4[(size_t)(4 * k4 + 3) * 32 + c];
#pragma unroll
            for (int jj = 0; jj < 8; ++jj) {
                float4 fv = s[(j0 * 8 + jj) * 16 + k4];
                acc[jj].x += fv.x * w0.x + fv.y * w1.x + fv.z * w2.x + fv.w * w3.x;
                acc[jj].y += fv.x * w0.y + fv.y * w1.y + fv.z * w2.y + fv.w * w3.y;
                acc[jj].z += fv.x * w0.z + fv.y * w1.z + fv.z * w2.z + fv.w * w3.z;
                acc[jj].w += fv.x * w0.w + fv.y * w1.w + fv.z * w2.w + fv.w * w3.w;
            }
        }
#pragma unroll
        for (int jj = 0; jj < 8; ++jj) {
            int n = n0 + j0 * 8 + jj;
            if (n < N) ((float4*)(dz + (size_t)n * OUT_DIM))[c] = acc[jj];
        }
    }
}

// ---------------------------------------------------------------------------
// CSR build: histogram -> device-wide exclusive scan (3 kernels) -> scatter
// ---------------------------------------------------------------------------
__global__ void k_hist(const int* __restrict__ dst, unsigned* __restrict__ counts, int E) {
    for (int i = blockIdx.x * blockDim.x + threadIdx.x; i < E; i += gridDim.x * blockDim.x)
        atomicAdd(&counts[dst[i]], 1u);
}

__global__ __launch_bounds__(SCH) void k_scan1(const unsigned* __restrict__ counts,
                                               unsigned* __restrict__ partials, int N) {
    int b = blockIdx.x, t = threadIdx.x;
    int idx = b * SCH + t;
    unsigned v = (idx < N) ? counts[idx] : 0u;
#pragma unroll
    for (int off = 32; off; off >>= 1) v += __shfl_xor(v, off);   // wave64 reduce
    __shared__ unsigned sw[SCH / 64];
    if ((t & 63) == 0) sw[t >> 6] = v;
    __syncthreads();
    if (t == 0) {
        unsigned s = 0;
#pragma unroll
        for (int i = 0; i < SCH / 64; ++i) s += sw[i];
        partials[b] = s;
    }
}

__global__ __launch_bounds__(1024) void k_scan2(unsigned* __restrict__ partials, int nblk) {
    __shared__ unsigned s[1024];
    int t = threadIdx.x;
    unsigned v = (t < nblk) ? partials[t] : 0u;
    s[t] = v;
    __syncthreads();
    for (int off = 1; off < 1024; off <<= 1) {
        unsigned u = (t >= off) ? s[t - off] : 0u;
        __syncthreads();
        s[t] += u;
        __syncthreads();
    }
    if (t < nblk) partials[t] = s[t] - v;
}

__global__ __launch_bounds__(SCH) void k_scan3(const unsigned* __restrict__ counts,
                                               const unsigned* __restrict__ partials,
                                               unsigned* __restrict__ offsets, int N) {
    int b = blockIdx.x, t = threadIdx.x;
    int idx = b * SCH + t;
    unsigned v = (idx < N) ? counts[idx] : 0u;
    __shared__ unsigned s[SCH];
    s[t] = v;
    __syncthreads();
    for (int off = 1; off < SCH; off <<= 1) {
        unsigned u = (t >= off) ? s[t - off] : 0u;
        __syncthreads();
        s[t] += u;
        __syncthreads();
    }
    unsigned base = partials[b];
    if (idx < N)  offsets[idx] = base + s[t] - v;
    if (idx == N - 1) offsets[N] = base + s[t];
}

__global__ void k_scatter(const int* __restrict__ dst, const int* __restrict__ src,
                          const unsigned* __restrict__ offsets,
                          unsigned* __restrict__ cursor, unsigned* __restrict__ csr, int E) {
    for (int i = blockIdx.x * blockDim.x + threadIdx.x; i < E; i += gridDim.x * blockDim.x) {
        int d = dst[i];
        unsigned pos = offsets[d] + atomicAdd(&cursor[d], 1u);
        csr[pos] = (unsigned)src[i];   // payload = source node id
    }
}

// ---------------------------------------------------------------------------
// Fused attention + aggregation. One 128-thread block per node, 4 groups of
// 32 lanes; each group keeps 8 edges in flight (32 z-rows / block).
//   out[n] = sum_e exp(<z[s_e], dz[n]>) * z[s_e]  /  sum_e exp(...)
// ---------------------------------------------------------------------------
__device__ __forceinline__ float dot4(float4 a, float4 b) {
    return a.x * b.x + a.y * b.y + a.z * b.z + a.w * b.w;
}
__device__ __forceinline__ float red32(float p) {
#pragma unroll
    for (int off = 16; off; off >>= 1) p += __shfl_xor(p, off);
    return p;
}

__global__ __launch_bounds__(128) void k_node(
        const float* __restrict__ z, const float* __restrict__ dz,
        const unsigned* __restrict__ offsets, const unsigned* __restrict__ csr,
        float* __restrict__ out, int N) {
    int n = blockIdx.x, t = threadIdx.x;
    int lane = t & 31, g = t >> 5;       // 4 groups of 32 lanes
    unsigned start = offsets[n];
    int deg = (int)(offsets[n + 1] - start);
    if (deg == 0) { out[(size_t)n * OUT_DIM + t] = 0.f; return; }

    float4 dzv = ((const float4*)(dz + (size_t)n * OUT_DIM))[lane];

    float4 acc = make_float4(0.f, 0.f, 0.f, 0.f);
    float denom = 0.f;

    int i = g;
    for (; i + 28 < deg; i += 32) {      // 8 edges in flight per group
        int sid[8];
#pragma unroll
        for (int u = 0; u < 8; ++u) sid[u] = (int)csr[start + i + 4 * u];
        float4 zr[8];
#pragma unroll
        for (int u = 0; u < 8; ++u)
            zr[u] = ((const float4*)(z + (size_t)sid[u] * OUT_DIM))[lane];
        float w[8];
#pragma unroll
        for (int u = 0; u < 8; ++u) w[u] = __expf(red32(dot4(zr[u], dzv)));
#pragma unroll
        for (int u = 0; u < 8; ++u) {
            denom += w[u];
            acc.x += w[u] * zr[u].x; acc.y += w[u] * zr[u].y;
            acc.z += w[u] * zr[u].z; acc.w += w[u] * zr[u].w;
        }
    }
    for (; i < deg; i += 4) {            // remainder
        int s0 = (int)csr[start + i];
        float4 z0 = ((const float4*)(z + (size_t)s0 * OUT_DIM))[lane];
        float w0 = __expf(red32(dot4(z0, dzv)));
        denom += w0;
        acc.x += w0 * z0.x; acc.y += w0 * z0.y;
        acc.z += w0 * z0.z; acc.w += w0 * z0.w;
    }

    __shared__ float s_acc[4][OUT_DIM];
    __shared__ float s_den[4];
    ((float4*)&s_acc[g][0])[lane] = acc;
    if (lane == 0) s_den[g] = denom;
    __syncthreads();
    float r = (s_acc[0][t] + s_acc[1][t]) + (s_acc[2][t] + s_acc[3][t]);
    float d = (s_den[0] + s_den[1]) + (s_den[2] + s_den[3]);
    out[(size_t)n * OUT_DIM + t] = r / d;
}

// ---------------------------------------------------------------------------
extern "C" void kernel_launch(void* const* d_in, const int* in_sizes, int n_in,
                              void* d_out, int out_size, void* d_ws, size_t ws_size,
                              hipStream_t stream) {
    const float* h    = (const float*)d_in[0];
    const float* feat = (const float*)d_in[1];
    const float* Wfc  = (const float*)d_in[2];
    const float* Wdst = (const float*)d_in[3];
    const int*   src  = (const int*)d_in[4];
    const int*   dst  = (const int*)d_in[5];
    float*       out  = (float*)d_out;

    int N = in_sizes[0] / IN_DIM;
    int E = in_sizes[4];

    char* ws = (char*)d_ws;
    float*    z        = (float*)ws;    ws += (size_t)N * OUT_DIM * sizeof(float);
    float*    dz       = (float*)ws;    ws += (size_t)N * OUT_DIM * sizeof(float);
    unsigned* counts   = (unsigned*)ws; ws += (size_t)N * sizeof(unsigned);
    unsigned* cursor   = (unsigned*)ws; ws += (size_t)N * sizeof(unsigned);
    unsigned* offsets  = (unsigned*)ws; ws += (size_t)(N + 1) * sizeof(unsigned);
    unsigned* partials = (unsigned*)ws; ws += (size_t)1024 * sizeof(unsigned);
    unsigned* csr      = (unsigned*)ws;

    int nbz  = (N + NB - 1) / NB;       // 782
    int nblk = (N + SCH - 1) / SCH;     // 196

    hipMemsetAsync(counts, 0, (size_t)2 * N * sizeof(unsigned), stream);

    k_linear <<<2 * nbz, 256, 0, stream>>>(h, feat, Wfc, Wdst, z, dz, N, nbz);
    k_hist   <<<1024, 256, 0, stream>>>(dst, counts, E);
    k_scan1  <<<nblk, SCH, 0, stream>>>(counts, partials, N);
    k_scan2  <<<1, 1024, 0, stream>>>(partials, nblk);
    k_scan3  <<<nblk, SCH, 0, stream>>>(counts, partials, offsets, N);
    k_scatter<<<1024, 256, 0, stream>>>(dst, src, offsets, cursor, csr, E);
    k_node   <<<N, 128, 0, stream>>>(z, dz, offsets, csr, out, N);
}

// Round 7
// 200.502 us; speedup vs baseline: 1.0434x; 1.0434x over previous
//
#include <hip/hip_runtime.h>
#include <math.h>

#define IN_DIM   128
#define OUT_DIM  128
#define FEAT_DIM 64
#define NB       64     // nodes per k_linear block
#define SCH      256    // scan chunk size

// ---------------------------------------------------------------------------
// z = h @ W_fc ; dz = feat @ W_dst.  256 threads/block, 64 nodes/block.
// Grid = 2*nbz blocks: first nbz do z, rest do dz (doubles TLP vs fused).
// Thread = (col-group c: 4 cols) x (node-group j0: 8 consecutive nodes).
// ---------------------------------------------------------------------------
__global__ __launch_bounds__(256) void k_linear(
        const float* __restrict__ h, const float* __restrict__ feat,
        const float* __restrict__ Wfc, const float* __restrict__ Wdst,
        float* __restrict__ z, float* __restrict__ dz, int N, int nbz) {
    int t  = threadIdx.x;        // 0..255
    int c  = t & 31;             // cols 4c..4c+3
    int j0 = t >> 5;             // 0..7 -> nodes n0 + 8*j0 + jj
    int b  = blockIdx.x;
    bool do_z = (b < nbz);
    int n0 = (do_z ? b : b - nbz) * NB;

    __shared__ float4 s[NB * 32];   // 32 KB

    float4 acc[8];
#pragma unroll
    for (int jj = 0; jj < 8; ++jj) acc[jj] = make_float4(0.f, 0.f, 0.f, 0.f);

    if (do_z) {
        for (int i = t; i < NB * 32; i += 256) {
            int row = i >> 5, col = i & 31;
            int n = min(n0 + row, N - 1);
            s[i] = ((const float4*)(h + (size_t)n * IN_DIM))[col];
        }
        __syncthreads();

        const float4* Wf4 = (const float4*)Wfc;
#pragma unroll 2
        for (int k4 = 0; k4 < IN_DIM / 4; ++k4) {
            float4 w0 = Wf4[(size_t)(4 * k4 + 0) * 32 + c];
            float4 w1 = Wf4[(size_t)(4 * k4 + 1) * 32 + c];
            float4 w2 = Wf4[(size_t)(4 * k4 + 2) * 32 + c];
            float4 w3 = Wf4[(size_t)(4 * k4 + 3) * 32 + c];
#pragma unroll
            for (int jj = 0; jj < 8; ++jj) {
                float4 hv = s[(j0 * 8 + jj) * 32 + k4];
                acc[jj].x += hv.x * w0.x + hv.y * w1.x + hv.z * w2.x + hv.w * w3.x;
                acc[jj].y += hv.x * w0.y + hv.y * w1.y + hv.z * w2.y + hv.w * w3.y;
                acc[jj].z += hv.x * w0.z + hv.y * w1.z + hv.z * w2.z + hv.w * w3.z;
                acc[jj].w += hv.x * w0.w + hv.y * w1.w + hv.z * w2.w + hv.w * w3.w;
            }
        }
#pragma unroll
        for (int jj = 0; jj < 8; ++jj) {
            int n = n0 + j0 * 8 + jj;
            if (n < N) ((float4*)(z + (size_t)n * OUT_DIM))[c] = acc[jj];
        }
    } else {
        for (int i = t; i < NB * 16; i += 256) {
            int row = i >> 4, col = i & 15;
            int n = min(n0 + row, N - 1);
            s[i] = ((const float4*)(feat + (size_t)n * FEAT_DIM))[col];
        }
        __syncthreads();

        const float4* Wd4 = (const float4*)Wdst;
#pragma unroll 2
        for (int k4 = 0; k4 < FEAT_DIM / 4; ++k4) {
            float4 w0 = Wd4[(size_t)(4 * k4 + 0) * 32 + c];
            float4 w1 = Wd4[(size_t)(4 * k4 + 1) * 32 + c];
            float4 w2 = Wd4[(size_t)(4 * k4 + 2) * 32 + c];
            float4 w3 = Wd4[(size_t)(4 * k4 + 3) * 32 + c];
#pragma unroll
            for (int jj = 0; jj < 8; ++jj) {
                float4 fv = s[(j0 * 8 + jj) * 16 + k4];
                acc[jj].x += fv.x * w0.x + fv.y * w1.x + fv.z * w2.x + fv.w * w3.x;
                acc[jj].y += fv.x * w0.y + fv.y * w1.y + fv.z * w2.y + fv.w * w3.y;
                acc[jj].z += fv.x * w0.z + fv.y * w1.z + fv.z * w2.z + fv.w * w3.z;
                acc[jj].w += fv.x * w0.w + fv.y * w1.w + fv.z * w2.w + fv.w * w3.w;
            }
        }
#pragma unroll
        for (int jj = 0; jj < 8; ++jj) {
            int n = n0 + j0 * 8 + jj;
            if (n < N) ((float4*)(dz + (size_t)n * OUT_DIM))[c] = acc[jj];
        }
    }
}

// ---------------------------------------------------------------------------
// CSR build: histogram -> device-wide exclusive scan (3 kernels) -> scatter
// ---------------------------------------------------------------------------
__global__ void k_hist(const int* __restrict__ dst, unsigned* __restrict__ counts, int E) {
    for (int i = blockIdx.x * blockDim.x + threadIdx.x; i < E; i += gridDim.x * blockDim.x)
        atomicAdd(&counts[dst[i]], 1u);
}

__global__ __launch_bounds__(SCH) void k_scan1(const unsigned* __restrict__ counts,
                                               unsigned* __restrict__ partials, int N) {
    int b = blockIdx.x, t = threadIdx.x;
    int idx = b * SCH + t;
    unsigned v = (idx < N) ? counts[idx] : 0u;
#pragma unroll
    for (int off = 32; off; off >>= 1) v += __shfl_xor(v, off);   // wave64 reduce
    __shared__ unsigned sw[SCH / 64];
    if ((t & 63) == 0) sw[t >> 6] = v;
    __syncthreads();
    if (t == 0) {
        unsigned s = 0;
#pragma unroll
        for (int i = 0; i < SCH / 64; ++i) s += sw[i];
        partials[b] = s;
    }
}

__global__ __launch_bounds__(1024) void k_scan2(unsigned* __restrict__ partials, int nblk) {
    __shared__ unsigned s[1024];
    int t = threadIdx.x;
    unsigned v = (t < nblk) ? partials[t] : 0u;
    s[t] = v;
    __syncthreads();
    for (int off = 1; off < 1024; off <<= 1) {
        unsigned u = (t >= off) ? s[t - off] : 0u;
        __syncthreads();
        s[t] += u;
        __syncthreads();
    }
    if (t < nblk) partials[t] = s[t] - v;
}

__global__ __launch_bounds__(SCH) void k_scan3(const unsigned* __restrict__ counts,
                                               const unsigned* __restrict__ partials,
                                               unsigned* __restrict__ offsets, int N) {
    int b = blockIdx.x, t = threadIdx.x;
    int idx = b * SCH + t;
    unsigned v = (idx < N) ? counts[idx] : 0u;
    __shared__ unsigned s[SCH];
    s[t] = v;
    __syncthreads();
    for (int off = 1; off < SCH; off <<= 1) {
        unsigned u = (t >= off) ? s[t - off] : 0u;
        __syncthreads();
        s[t] += u;
        __syncthreads();
    }
    unsigned base = partials[b];
    if (idx < N)  offsets[idx] = base + s[t] - v;
    if (idx == N - 1) offsets[N] = base + s[t];
}

__global__ void k_scatter(const int* __restrict__ dst, const int* __restrict__ src,
                          const unsigned* __restrict__ offsets,
                          unsigned* __restrict__ cursor, unsigned* __restrict__ csr, int E) {
    for (int i = blockIdx.x * blockDim.x + threadIdx.x; i < E; i += gridDim.x * blockDim.x) {
        int d = dst[i];
        unsigned pos = offsets[d] + atomicAdd(&cursor[d], 1u);
        csr[pos] = (unsigned)src[i];   // payload = source node id
    }
}

// ---------------------------------------------------------------------------
// Fused attention + aggregation. ONE 64-LANE WAVE PER NODE (4 nodes/block).
// Mean deg = 16 => 4-deep unrolled path covers deg>=4 (~all nodes).
// No LDS, no __syncthreads; wave writes its 128-float row directly.
//   out[n] = sum_e exp(<z[s_e], dz[n]>) * z[s_e]  /  sum_e exp(...)
// ---------------------------------------------------------------------------
__device__ __forceinline__ float red64(float p) {
#pragma unroll
    for (int off = 32; off; off >>= 1) p += __shfl_xor(p, off);
    return p;
}

__global__ __launch_bounds__(256) void k_node(
        const float* __restrict__ z, const float* __restrict__ dz,
        const unsigned* __restrict__ offsets, const unsigned* __restrict__ csr,
        float* __restrict__ out, int N) {
    int lane = threadIdx.x & 63;
    int wv   = threadIdx.x >> 6;          // 0..3
    int n = blockIdx.x * 4 + wv;
    if (n >= N) return;

    unsigned start = offsets[n];
    int deg = (int)(offsets[n + 1] - start);
    float2* orow = (float2*)(out + (size_t)n * OUT_DIM);
    if (deg == 0) { orow[lane] = make_float2(0.f, 0.f); return; }

    float2 dzv = ((const float2*)(dz + (size_t)n * OUT_DIM))[lane];

    float ax = 0.f, ay = 0.f, denom = 0.f;
    int i = 0;
    for (; i + 3 < deg; i += 4) {         // 4 rows in flight per wave
        int s0 = (int)csr[start + i];
        int s1 = (int)csr[start + i + 1];
        int s2 = (int)csr[start + i + 2];
        int s3 = (int)csr[start + i + 3];
        float2 z0 = ((const float2*)(z + (size_t)s0 * OUT_DIM))[lane];
        float2 z1 = ((const float2*)(z + (size_t)s1 * OUT_DIM))[lane];
        float2 z2 = ((const float2*)(z + (size_t)s2 * OUT_DIM))[lane];
        float2 z3 = ((const float2*)(z + (size_t)s3 * OUT_DIM))[lane];
        float p0 = red64(z0.x * dzv.x + z0.y * dzv.y);
        float p1 = red64(z1.x * dzv.x + z1.y * dzv.y);
        float p2 = red64(z2.x * dzv.x + z2.y * dzv.y);
        float p3 = red64(z3.x * dzv.x + z3.y * dzv.y);
        float w0 = __expf(p0), w1 = __expf(p1), w2 = __expf(p2), w3 = __expf(p3);
        denom += (w0 + w1) + (w2 + w3);
        ax += w0 * z0.x + w1 * z1.x + w2 * z2.x + w3 * z3.x;
        ay += w0 * z0.y + w1 * z1.y + w2 * z2.y + w3 * z3.y;
    }
    for (; i < deg; ++i) {                // remainder (deg%4)
        int s0 = (int)csr[start + i];
        float2 z0 = ((const float2*)(z + (size_t)s0 * OUT_DIM))[lane];
        float w0 = __expf(red64(z0.x * dzv.x + z0.y * dzv.y));
        denom += w0;
        ax += w0 * z0.x;
        ay += w0 * z0.y;
    }

    float inv = 1.f / denom;
    orow[lane] = make_float2(ax * inv, ay * inv);
}

// ---------------------------------------------------------------------------
extern "C" void kernel_launch(void* const* d_in, const int* in_sizes, int n_in,
                              void* d_out, int out_size, void* d_ws, size_t ws_size,
                              hipStream_t stream) {
    const float* h    = (const float*)d_in[0];
    const float* feat = (const float*)d_in[1];
    const float* Wfc  = (const float*)d_in[2];
    const float* Wdst = (const float*)d_in[3];
    const int*   src  = (const int*)d_in[4];
    const int*   dst  = (const int*)d_in[5];
    float*       out  = (float*)d_out;

    int N = in_sizes[0] / IN_DIM;
    int E = in_sizes[4];

    char* ws = (char*)d_ws;
    float*    z        = (float*)ws;    ws += (size_t)N * OUT_DIM * sizeof(float);
    float*    dz       = (float*)ws;    ws += (size_t)N * OUT_DIM * sizeof(float);
    unsigned* counts   = (unsigned*)ws; ws += (size_t)N * sizeof(unsigned);
    unsigned* cursor   = (unsigned*)ws; ws += (size_t)N * sizeof(unsigned);
    unsigned* offsets  = (unsigned*)ws; ws += (size_t)(N + 1) * sizeof(unsigned);
    unsigned* partials = (unsigned*)ws; ws += (size_t)1024 * sizeof(unsigned);
    unsigned* csr      = (unsigned*)ws;

    int nbz  = (N + NB - 1) / NB;       // 782
    int nblk = (N + SCH - 1) / SCH;     // 196

    hipMemsetAsync(counts, 0, (size_t)2 * N * sizeof(unsigned), stream);

    k_linear <<<2 * nbz, 256, 0, stream>>>(h, feat, Wfc, Wdst, z, dz, N, nbz);
    k_hist   <<<1024, 256, 0, stream>>>(dst, counts, E);
    k_scan1  <<<nblk, SCH, 0, stream>>>(counts, partials, N);
    k_scan2  <<<1, 1024, 0, stream>>>(partials, nblk);
    k_scan3  <<<nblk, SCH, 0, stream>>>(counts, partials, offsets, N);
    k_scatter<<<1024, 256, 0, stream>>>(dst, src, offsets, cursor, csr, E);
    k_node   <<<(N + 3) / 4, 256, 0, stream>>>(z, dz, offsets, csr, out, N);
}

// Round 8
// 195.617 us; speedup vs baseline: 1.0695x; 1.0250x over previous
//
#include <hip/hip_runtime.h>
#include <math.h>

#define IN_DIM   128
#define OUT_DIM  128
#define FEAT_DIM 64
#define NB       64     // nodes per k_linear block
#define SCH      256    // scan chunk size

// ---------------------------------------------------------------------------
// z = h @ W_fc ; dz = feat @ W_dst.  256 threads/block, 64 nodes/block.
// Grid = 2*nbz blocks: first nbz do z, rest do dz.
// ---------------------------------------------------------------------------
__global__ __launch_bounds__(256) void k_linear(
        const float* __restrict__ h, const float* __restrict__ feat,
        const float* __restrict__ Wfc, const float* __restrict__ Wdst,
        float* __restrict__ z, float* __restrict__ dz, int N, int nbz) {
    int t  = threadIdx.x;        // 0..255
    int c  = t & 31;             // cols 4c..4c+3
    int j0 = t >> 5;             // 0..7 -> nodes n0 + 8*j0 + jj
    int b  = blockIdx.x;
    bool do_z = (b < nbz);
    int n0 = (do_z ? b : b - nbz) * NB;

    __shared__ float4 s[NB * 32];   // 32 KB

    float4 acc[8];
#pragma unroll
    for (int jj = 0; jj < 8; ++jj) acc[jj] = make_float4(0.f, 0.f, 0.f, 0.f);

    if (do_z) {
        for (int i = t; i < NB * 32; i += 256) {
            int row = i >> 5, col = i & 31;
            int n = min(n0 + row, N - 1);
            s[i] = ((const float4*)(h + (size_t)n * IN_DIM))[col];
        }
        __syncthreads();

        const float4* Wf4 = (const float4*)Wfc;
#pragma unroll 2
        for (int k4 = 0; k4 < IN_DIM / 4; ++k4) {
            float4 w0 = Wf4[(size_t)(4 * k4 + 0) * 32 + c];
            float4 w1 = Wf4[(size_t)(4 * k4 + 1) * 32 + c];
            float4 w2 = Wf4[(size_t)(4 * k4 + 2) * 32 + c];
            float4 w3 = Wf4[(size_t)(4 * k4 + 3) * 32 + c];
#pragma unroll
            for (int jj = 0; jj < 8; ++jj) {
                float4 hv = s[(j0 * 8 + jj) * 32 + k4];
                acc[jj].x += hv.x * w0.x + hv.y * w1.x + hv.z * w2.x + hv.w * w3.x;
                acc[jj].y += hv.x * w0.y + hv.y * w1.y + hv.z * w2.y + hv.w * w3.y;
                acc[jj].z += hv.x * w0.z + hv.y * w1.z + hv.z * w2.z + hv.w * w3.z;
                acc[jj].w += hv.x * w0.w + hv.y * w1.w + hv.z * w2.w + hv.w * w3.w;
            }
        }
#pragma unroll
        for (int jj = 0; jj < 8; ++jj) {
            int n = n0 + j0 * 8 + jj;
            if (n < N) ((float4*)(z + (size_t)n * OUT_DIM))[c] = acc[jj];
        }
    } else {
        for (int i = t; i < NB * 16; i += 256) {
            int row = i >> 4, col = i & 15;
            int n = min(n0 + row, N - 1);
            s[i] = ((const float4*)(feat + (size_t)n * FEAT_DIM))[col];
        }
        __syncthreads();

        const float4* Wd4 = (const float4*)Wdst;
#pragma unroll 2
        for (int k4 = 0; k4 < FEAT_DIM / 4; ++k4) {
            float4 w0 = Wd4[(size_t)(4 * k4 + 0) * 32 + c];
            float4 w1 = Wd4[(size_t)(4 * k4 + 1) * 32 + c];
            float4 w2 = Wd4[(size_t)(4 * k4 + 2) * 32 + c];
            float4 w3 = Wd4[(size_t)(4 * k4 + 3) * 32 + c];
#pragma unroll
            for (int jj = 0; jj < 8; ++jj) {
                float4 fv = s[(j0 * 8 + jj) * 16 + k4];
                acc[jj].x += fv.x * w0.x + fv.y * w1.x + fv.z * w2.x + fv.w * w3.x;
                acc[jj].y += fv.x * w0.y + fv.y * w1.y + fv.z * w2.y + fv.w * w3.y;
                acc[jj].z += fv.x * w0.z + fv.y * w1.z + fv.z * w2.z + fv.w * w3.z;
                acc[jj].w += fv.x * w0.w + fv.y * w1.w + fv.z * w2.w + fv.w * w3.w;
            }
        }
#pragma unroll
        for (int jj = 0; jj < 8; ++jj) {
            int n = n0 + j0 * 8 + jj;
            if (n < N) ((float4*)(dz + (size_t)n * OUT_DIM))[c] = acc[jj];
        }
    }
}

// ---------------------------------------------------------------------------
// CSR build: histogram -> device-wide exclusive scan (3 kernels) -> scatter
// ---------------------------------------------------------------------------
__global__ void k_hist(const int* __restrict__ dst, unsigned* __restrict__ counts, int E) {
    for (int i = blockIdx.x * blockDim.x + threadIdx.x; i < E; i += gridDim.x * blockDim.x)
        atomicAdd(&counts[dst[i]], 1u);
}

__global__ __launch_bounds__(SCH) void k_scan1(const unsigned* __restrict__ counts,
                                               unsigned* __restrict__ partials, int N) {
    int b = blockIdx.x, t = threadIdx.x;
    int idx = b * SCH + t;
    unsigned v = (idx < N) ? counts[idx] : 0u;
#pragma unroll
    for (int off = 32; off; off >>= 1) v += __shfl_xor(v, off);   // wave64 reduce
    __shared__ unsigned sw[SCH / 64];
    if ((t & 63) == 0) sw[t >> 6] = v;
    __syncthreads();
    if (t == 0) {
        unsigned s = 0;
#pragma unroll
        for (int i = 0; i < SCH / 64; ++i) s += sw[i];
        partials[b] = s;
    }
}

__global__ __launch_bounds__(1024) void k_scan2(unsigned* __restrict__ partials, int nblk) {
    __shared__ unsigned s[1024];
    int t = threadIdx.x;
    unsigned v = (t < nblk) ? partials[t] : 0u;
    s[t] = v;
    __syncthreads();
    for (int off = 1; off < 1024; off <<= 1) {
        unsigned u = (t >= off) ? s[t - off] : 0u;
        __syncthreads();
        s[t] += u;
        __syncthreads();
    }
    if (t < nblk) partials[t] = s[t] - v;
}

__global__ __launch_bounds__(SCH) void k_scan3(const unsigned* __restrict__ counts,
                                               const unsigned* __restrict__ partials,
                                               unsigned* __restrict__ offsets, int N) {
    int b = blockIdx.x, t = threadIdx.x;
    int idx = b * SCH + t;
    unsigned v = (idx < N) ? counts[idx] : 0u;
    __shared__ unsigned s[SCH];
    s[t] = v;
    __syncthreads();
    for (int off = 1; off < SCH; off <<= 1) {
        unsigned u = (t >= off) ? s[t - off] : 0u;
        __syncthreads();
        s[t] += u;
        __syncthreads();
    }
    unsigned base = partials[b];
    if (idx < N)  offsets[idx] = base + s[t] - v;
    if (idx == N - 1) offsets[N] = base + s[t];
}

__global__ void k_scatter(const int* __restrict__ dst, const int* __restrict__ src,
                          const unsigned* __restrict__ offsets,
                          unsigned* __restrict__ cursor, unsigned* __restrict__ csr, int E) {
    for (int i = blockIdx.x * blockDim.x + threadIdx.x; i < E; i += gridDim.x * blockDim.x) {
        int d = dst[i];
        unsigned pos = offsets[d] + atomicAdd(&cursor[d], 1u);
        csr[pos] = (unsigned)src[i];   // payload = source node id
    }
}

// ---------------------------------------------------------------------------
// Fused attention + aggregation. One 64-lane wave per node (4 nodes/block).
// 16 LANES PER EDGE: lane l owns row dims [(l&15)*8, +8); group g = l>>4 owns
// edge i+g. One wave-wide float4 load pair moves 4 rows; dot-reduce is a
// 4-level shfl tree SHARED by the 4 edges; one exp instr per 4 edges.
// Ragged tail handled by predication (w=0), no serial remainder.
// ---------------------------------------------------------------------------
__device__ __forceinline__ float dot4(float4 a, float4 b) {
    return a.x * b.x + a.y * b.y + a.z * b.z + a.w * b.w;
}

__global__ __launch_bounds__(256) void k_node(
        const float* __restrict__ z, const float* __restrict__ dz,
        const unsigned* __restrict__ offsets, const unsigned* __restrict__ csr,
        float* __restrict__ out, int N) {
    int lane = threadIdx.x & 63;
    int wv   = threadIdx.x >> 6;          // 0..3
    int g    = lane >> 4;                 // edge slot 0..3
    int l16  = lane & 15;                 // row chunk 0..15
    int n = blockIdx.x * 4 + wv;
    if (n >= N) return;

    unsigned start = offsets[n];
    int deg = (int)(offsets[n + 1] - start);
    float4* orow = (float4*)(out + (size_t)n * OUT_DIM);
    if (deg == 0) {
        if (g == 0) {
            orow[2 * l16]     = make_float4(0.f, 0.f, 0.f, 0.f);
            orow[2 * l16 + 1] = make_float4(0.f, 0.f, 0.f, 0.f);
        }
        return;
    }

    const float4* dzp = (const float4*)(dz + (size_t)n * OUT_DIM);
    float4 d0 = dzp[2 * l16];
    float4 d1 = dzp[2 * l16 + 1];

    float4 a0 = make_float4(0.f, 0.f, 0.f, 0.f);
    float4 a1 = make_float4(0.f, 0.f, 0.f, 0.f);
    float denom = 0.f;

    for (int i = 0; i < deg; i += 8) {
        int eA = i + g;
        int eB = i + 4 + g;
        bool vA = eA < deg;
        bool vB = eB < deg;
        int sA = vA ? (int)csr[start + eA] : 0;
        int sB = vB ? (int)csr[start + eB] : 0;
        const float4* zpA = (const float4*)(z + (size_t)sA * OUT_DIM);
        const float4* zpB = (const float4*)(z + (size_t)sB * OUT_DIM);
        // 4 wave-wide loads = 8 rows in flight
        float4 zA0 = zpA[2 * l16];
        float4 zA1 = zpA[2 * l16 + 1];
        float4 zB0 = zpB[2 * l16];
        float4 zB1 = zpB[2 * l16 + 1];

        float pA = dot4(zA0, d0) + dot4(zA1, d1);
        float pB = dot4(zB0, d0) + dot4(zB1, d1);
#pragma unroll
        for (int off = 1; off <= 8; off <<= 1) {       // reduce within 16-lane group
            pA += __shfl_xor(pA, off);
            pB += __shfl_xor(pB, off);
        }
        float wA = vA ? __expf(pA) : 0.f;
        float wB = vB ? __expf(pB) : 0.f;
        denom += wA + wB;
        a0.x += wA * zA0.x + wB * zB0.x;  a0.y += wA * zA0.y + wB * zB0.y;
        a0.z += wA * zA0.z + wB * zB0.z;  a0.w += wA * zA0.w + wB * zB0.w;
        a1.x += wA * zA1.x + wB * zB1.x;  a1.y += wA * zA1.y + wB * zB1.y;
        a1.z += wA * zA1.z + wB * zB1.z;  a1.w += wA * zA1.w + wB * zB1.w;
    }

    // fold the 4 edge-groups together (lanes l, l^16, l^32, l^48)
#pragma unroll
    for (int off = 16; off <= 32; off <<= 1) {
        a0.x += __shfl_xor(a0.x, off); a0.y += __shfl_xor(a0.y, off);
        a0.z += __shfl_xor(a0.z, off); a0.w += __shfl_xor(a0.w, off);
        a1.x += __shfl_xor(a1.x, off); a1.y += __shfl_xor(a1.y, off);
        a1.z += __shfl_xor(a1.z, off); a1.w += __shfl_xor(a1.w, off);
        denom += __shfl_xor(denom, off);
    }

    if (g == 0) {
        float inv = 1.f / denom;
        orow[2 * l16]     = make_float4(a0.x * inv, a0.y * inv, a0.z * inv, a0.w * inv);
        orow[2 * l16 + 1] = make_float4(a1.x * inv, a1.y * inv, a1.z * inv, a1.w * inv);
    }
}

// ---------------------------------------------------------------------------
extern "C" void kernel_launch(void* const* d_in, const int* in_sizes, int n_in,
                              void* d_out, int out_size, void* d_ws, size_t ws_size,
                              hipStream_t stream) {
    const float* h    = (const float*)d_in[0];
    const float* feat = (const float*)d_in[1];
    const float* Wfc  = (const float*)d_in[2];
    const float* Wdst = (const float*)d_in[3];
    const int*   src  = (const int*)d_in[4];
    const int*   dst  = (const int*)d_in[5];
    float*       out  = (float*)d_out;

    int N = in_sizes[0] / IN_DIM;
    int E = in_sizes[4];

    char* ws = (char*)d_ws;
    float*    z        = (float*)ws;    ws += (size_t)N * OUT_DIM * sizeof(float);
    float*    dz       = (float*)ws;    ws += (size_t)N * OUT_DIM * sizeof(float);
    unsigned* counts   = (unsigned*)ws; ws += (size_t)N * sizeof(unsigned);
    unsigned* cursor   = (unsigned*)ws; ws += (size_t)N * sizeof(unsigned);
    unsigned* offsets  = (unsigned*)ws; ws += (size_t)(N + 1) * sizeof(unsigned);
    unsigned* partials = (unsigned*)ws; ws += (size_t)1024 * sizeof(unsigned);
    unsigned* csr      = (unsigned*)ws;

    int nbz  = (N + NB - 1) / NB;       // 782
    int nblk = (N + SCH - 1) / SCH;     // 196

    hipMemsetAsync(counts, 0, (size_t)2 * N * sizeof(unsigned), stream);

    k_linear <<<2 * nbz, 256, 0, stream>>>(h, feat, Wfc, Wdst, z, dz, N, nbz);
    k_hist   <<<1024, 256, 0, stream>>>(dst, counts, E);
    k_scan1  <<<nblk, SCH, 0, stream>>>(counts, partials, N);
    k_scan2  <<<1, 1024, 0, stream>>>(partials, nblk);
    k_scan3  <<<nblk, SCH, 0, stream>>>(counts, partials, offsets, N);
    k_scatter<<<1024, 256, 0, stream>>>(dst, src, offsets, cursor, csr, E);
    k_node   <<<(N + 3) / 4, 256, 0, stream>>>(z, dz, offsets, csr, out, N);
}

// Round 10
// 179.317 us; speedup vs baseline: 1.1667x; 1.0909x over previous
//
#include <hip/hip_runtime.h>
#include <hip/hip_fp16.h>
#include <math.h>

#define IN_DIM   128
#define OUT_DIM  128
#define FEAT_DIM 64
#define NB       64     // nodes per k_linear block
#define SCH      256    // scan chunk size

__device__ __forceinline__ float2 h2f2(unsigned u) {
    __half2 h = *reinterpret_cast<const __half2*>(&u);
    return __half22float2(h);
}

// ---------------------------------------------------------------------------
// z = fp16(h @ W_fc) ; dz = feat @ W_dst.  256 threads/block, 64 nodes/block.
// Grid = 2*nbz blocks: first nbz do z (fp16 out), rest do dz (fp32 out).
// ---------------------------------------------------------------------------
__global__ __launch_bounds__(256) void k_linear(
        const float* __restrict__ h, const float* __restrict__ feat,
        const float* __restrict__ Wfc, const float* __restrict__ Wdst,
        unsigned short* __restrict__ z_h, float* __restrict__ dz, int N, int nbz) {
    int t  = threadIdx.x;        // 0..255
    int c  = t & 31;             // cols 4c..4c+3
    int j0 = t >> 5;             // 0..7 -> nodes n0 + 8*j0 + jj
    int b  = blockIdx.x;
    bool do_z = (b < nbz);
    int n0 = (do_z ? b : b - nbz) * NB;

    __shared__ float4 s[NB * 32];   // 32 KB

    float4 acc[8];
#pragma unroll
    for (int jj = 0; jj < 8; ++jj) acc[jj] = make_float4(0.f, 0.f, 0.f, 0.f);

    if (do_z) {
        for (int i = t; i < NB * 32; i += 256) {
            int row = i >> 5, col = i & 31;
            int n = min(n0 + row, N - 1);
            s[i] = ((const float4*)(h + (size_t)n * IN_DIM))[col];
        }
        __syncthreads();

        const float4* Wf4 = (const float4*)Wfc;
#pragma unroll 2
        for (int k4 = 0; k4 < IN_DIM / 4; ++k4) {
            float4 w0 = Wf4[(size_t)(4 * k4 + 0) * 32 + c];
            float4 w1 = Wf4[(size_t)(4 * k4 + 1) * 32 + c];
            float4 w2 = Wf4[(size_t)(4 * k4 + 2) * 32 + c];
            float4 w3 = Wf4[(size_t)(4 * k4 + 3) * 32 + c];
#pragma unroll
            for (int jj = 0; jj < 8; ++jj) {
                float4 hv = s[(j0 * 8 + jj) * 32 + k4];
                acc[jj].x += hv.x * w0.x + hv.y * w1.x + hv.z * w2.x + hv.w * w3.x;
                acc[jj].y += hv.x * w0.y + hv.y * w1.y + hv.z * w2.y + hv.w * w3.y;
                acc[jj].z += hv.x * w0.z + hv.y * w1.z + hv.z * w2.z + hv.w * w3.z;
                acc[jj].w += hv.x * w0.w + hv.y * w1.w + hv.z * w2.w + hv.w * w3.w;
            }
        }
#pragma unroll
        for (int jj = 0; jj < 8; ++jj) {
            int n = n0 + j0 * 8 + jj;
            if (n < N) {
                __half2 p0 = __floats2half2_rn(acc[jj].x, acc[jj].y);
                __half2 p1 = __floats2half2_rn(acc[jj].z, acc[jj].w);
                uint2 pk;
                pk.x = *reinterpret_cast<unsigned*>(&p0);
                pk.y = *reinterpret_cast<unsigned*>(&p1);
                ((uint2*)(z_h + (size_t)n * OUT_DIM))[c] = pk;
            }
        }
    } else {
        for (int i = t; i < NB * 16; i += 256) {
            int row = i >> 4, col = i & 15;
            int n = min(n0 + row, N - 1);
            s[i] = ((const float4*)(feat + (size_t)n * FEAT_DIM))[col];
        }
        __syncthreads();

        const float4* Wd4 = (const float4*)Wdst;
#pragma unroll 2
        for (int k4 = 0; k4 < FEAT_DIM / 4; ++k4) {
            float4 w0 = Wd4[(size_t)(4 * k4 + 0) * 32 + c];
            float4 w1 = Wd4[(size_t)(4 * k4 + 1) * 32 + c];
            float4 w2 = Wd4[(size_t)(4 * k4 + 2) * 32 + c];
            float4 w3 = Wd4[(size_t)(4 * k4 + 3) * 32 + c];
#pragma unroll
            for (int jj = 0; jj < 8; ++jj) {
                float4 fv = s[(j0 * 8 + jj) * 16 + k4];
                acc[jj].x += fv.x * w0.x + fv.y * w1.x + fv.z * w2.x + fv.w * w3.x;
                acc[jj].y += fv.x * w0.y + fv.y * w1.y + fv.z * w2.y + fv.w * w3.y;
                acc[jj].z += fv.x * w0.z + fv.y * w1.z + fv.z * w2.z + fv.w * w3.z;
                acc[jj].w += fv.x * w0.w + fv.y * w1.w + fv.z * w2.w + fv.w * w3.w;
            }
        }
#pragma unroll
        for (int jj = 0; jj < 8; ++jj) {
            int n = n0 + j0 * 8 + jj;
            if (n < N) ((float4*)(dz + (size_t)n * OUT_DIM))[c] = acc[jj];
        }
    }
}

// ---------------------------------------------------------------------------
// CSR build: histogram -> device-wide exclusive scan (3 kernels) -> scatter
// ---------------------------------------------------------------------------
__global__ void k_hist(const int* __restrict__ dst, unsigned* __restrict__ counts, int E) {
    for (int i = blockIdx.x * blockDim.x + threadIdx.x; i < E; i += gridDim.x * blockDim.x)
        atomicAdd(&counts[dst[i]], 1u);
}

__global__ __launch_bounds__(SCH) void k_scan1(const unsigned* __restrict__ counts,
                                               unsigned* __restrict__ partials, int N) {
    int b = blockIdx.x, t = threadIdx.x;
    int idx = b * SCH + t;
    unsigned v = (idx < N) ? counts[idx] : 0u;
#pragma unroll
    for (int off = 32; off; off >>= 1) v += __shfl_xor(v, off);   // wave64 reduce
    __shared__ unsigned sw[SCH / 64];
    if ((t & 63) == 0) sw[t >> 6] = v;
    __syncthreads();
    if (t == 0) {
        unsigned s = 0;
#pragma unroll
        for (int i = 0; i < SCH / 64; ++i) s += sw[i];
        partials[b] = s;
    }
}

__global__ __launch_bounds__(1024) void k_scan2(unsigned* __restrict__ partials, int nblk) {
    __shared__ unsigned s[1024];
    int t = threadIdx.x;
    unsigned v = (t < nblk) ? partials[t] : 0u;
    s[t] = v;
    __syncthreads();
    for (int off = 1; off < 1024; off <<= 1) {
        unsigned u = (t >= off) ? s[t - off] : 0u;
        __syncthreads();
        s[t] += u;
        __syncthreads();
    }
    if (t < nblk) partials[t] = s[t] - v;
}

__global__ __launch_bounds__(SCH) void k_scan3(const unsigned* __restrict__ counts,
                                               const unsigned* __restrict__ partials,
                                               unsigned* __restrict__ offsets, int N) {
    int b = blockIdx.x, t = threadIdx.x;
    int idx = b * SCH + t;
    unsigned v = (idx < N) ? counts[idx] : 0u;
    __shared__ unsigned s[SCH];
    s[t] = v;
    __syncthreads();
    for (int off = 1; off < SCH; off <<= 1) {
        unsigned u = (t >= off) ? s[t - off] : 0u;
        __syncthreads();
        s[t] += u;
        __syncthreads();
    }
    unsigned base = partials[b];
    if (idx < N)  offsets[idx] = base + s[t] - v;
    if (idx == N - 1) offsets[N] = base + s[t];
}

__global__ void k_scatter(const int* __restrict__ dst, const int* __restrict__ src,
                          const unsigned* __restrict__ offsets,
                          unsigned* __restrict__ cursor, unsigned* __restrict__ csr, int E) {
    for (int i = blockIdx.x * blockDim.x + threadIdx.x; i < E; i += gridDim.x * blockDim.x) {
        int d = dst[i];
        unsigned pos = offsets[d] + atomicAdd(&cursor[d], 1u);
        csr[pos] = (unsigned)src[i];   // payload = source node id
    }
}

// ---------------------------------------------------------------------------
// Fused attention + aggregation. One 64-lane wave per node (4 nodes/block).
// 16 lanes per edge; z rows gathered in FP16 (256 B/row, one uint4/lane),
// unpacked to fp32 for dot + accumulate. dz stays fp32.
// ---------------------------------------------------------------------------
__global__ __launch_bounds__(256) void k_node(
        const unsigned short* __restrict__ z_h, const float* __restrict__ dz,
        const unsigned* __restrict__ offsets, const unsigned* __restrict__ csr,
        float* __restrict__ out, int N) {
    int lane = threadIdx.x & 63;
    int wv   = threadIdx.x >> 6;          // 0..3
    int g    = lane >> 4;                 // edge slot 0..3
    int l16  = lane & 15;                 // row chunk: dims [8*l16, 8*l16+8)
    int n = blockIdx.x * 4 + wv;
    if (n >= N) return;

    unsigned start = offsets[n];
    int deg = (int)(offsets[n + 1] - start);
    float4* orow = (float4*)(out + (size_t)n * OUT_DIM);
    if (deg == 0) {
        if (g == 0) {
            orow[2 * l16]     = make_float4(0.f, 0.f, 0.f, 0.f);
            orow[2 * l16 + 1] = make_float4(0.f, 0.f, 0.f, 0.f);
        }
        return;
    }

    const float4* dzp = (const float4*)(dz + (size_t)n * OUT_DIM);
    float4 d0 = dzp[2 * l16];
    float4 d1 = dzp[2 * l16 + 1];

    float a[8];
#pragma unroll
    for (int k = 0; k < 8; ++k) a[k] = 0.f;
    float denom = 0.f;

    for (int i = 0; i < deg; i += 8) {
        int eA = i + g;
        int eB = i + 4 + g;
        bool vA = eA < deg;
        bool vB = eB < deg;
        int sA = vA ? (int)csr[start + eA] : 0;
        int sB = vB ? (int)csr[start + eB] : 0;
        // one 16B load per slot = 8 fp16 dims
        uint4 qA = ((const uint4*)(z_h + (size_t)sA * OUT_DIM))[l16];
        uint4 qB = ((const uint4*)(z_h + (size_t)sB * OUT_DIM))[l16];

        float2 zA01 = h2f2(qA.x), zA23 = h2f2(qA.y), zA45 = h2f2(qA.z), zA67 = h2f2(qA.w);
        float2 zB01 = h2f2(qB.x), zB23 = h2f2(qB.y), zB45 = h2f2(qB.z), zB67 = h2f2(qB.w);

        float pA = zA01.x * d0.x + zA01.y * d0.y + zA23.x * d0.z + zA23.y * d0.w
                 + zA45.x * d1.x + zA45.y * d1.y + zA67.x * d1.z + zA67.y * d1.w;
        float pB = zB01.x * d0.x + zB01.y * d0.y + zB23.x * d0.z + zB23.y * d0.w
                 + zB45.x * d1.x + zB45.y * d1.y + zB67.x * d1.z + zB67.y * d1.w;
#pragma unroll
        for (int off = 1; off <= 8; off <<= 1) {   // reduce within 16-lane group
            pA += __shfl_xor(pA, off);
            pB += __shfl_xor(pB, off);
        }
        float wA = vA ? __expf(pA) : 0.f;
        float wB = vB ? __expf(pB) : 0.f;
        denom += wA + wB;
        a[0] += wA * zA01.x + wB * zB01.x;  a[1] += wA * zA01.y + wB * zB01.y;
        a[2] += wA * zA23.x + wB * zB23.x;  a[3] += wA * zA23.y + wB * zB23.y;
        a[4] += wA * zA45.x + wB * zB45.x;  a[5] += wA * zA45.y + wB * zB45.y;
        a[6] += wA * zA67.x + wB * zB67.x;  a[7] += wA * zA67.y + wB * zB67.y;
    }

    // fold the 4 edge-groups together (lanes l, l^16, l^32, l^48)
#pragma unroll
    for (int off = 16; off <= 32; off <<= 1) {
#pragma unroll
        for (int k = 0; k < 8; ++k) a[k] += __shfl_xor(a[k], off);
        denom += __shfl_xor(denom, off);
    }

    if (g == 0) {
        float inv = 1.f / denom;
        orow[2 * l16]     = make_float4(a[0] * inv, a[1] * inv, a[2] * inv, a[3] * inv);
        orow[2 * l16 + 1] = make_float4(a[4] * inv, a[5] * inv, a[6] * inv, a[7] * inv);
    }
}

// ---------------------------------------------------------------------------
extern "C" void kernel_launch(void* const* d_in, const int* in_sizes, int n_in,
                              void* d_out, int out_size, void* d_ws, size_t ws_size,
                              hipStream_t stream) {
    const float* h    = (const float*)d_in[0];
    const float* feat = (const float*)d_in[1];
    const float* Wfc  = (const float*)d_in[2];
    const float* Wdst = (const float*)d_in[3];
    const int*   src  = (const int*)d_in[4];
    const int*   dst  = (const int*)d_in[5];
    float*       out  = (float*)d_out;

    int N = in_sizes[0] / IN_DIM;
    int E = in_sizes[4];

    char* ws = (char*)d_ws;
    unsigned short* z_h = (unsigned short*)ws; ws += (size_t)N * OUT_DIM * sizeof(unsigned short);
    float*    dz       = (float*)ws;    ws += (size_t)N * OUT_DIM * sizeof(float);
    unsigned* counts   = (unsigned*)ws; ws += (size_t)N * sizeof(unsigned);
    unsigned* cursor   = (unsigned*)ws; ws += (size_t)N * sizeof(unsigned);
    unsigned* offsets  = (unsigned*)ws; ws += (size_t)(N + 1) * sizeof(unsigned);
    unsigned* partials = (unsigned*)ws; ws += (size_t)1024 * sizeof(unsigned);
    unsigned* csr      = (unsigned*)ws;

    int nbz  = (N + NB - 1) / NB;       // 782
    int nblk = (N + SCH - 1) / SCH;     // 196

    hipMemsetAsync(counts, 0, (size_t)2 * N * sizeof(unsigned), stream);

    k_linear <<<2 * nbz, 256, 0, stream>>>(h, feat, Wfc, Wdst, z_h, dz, N, nbz);
    k_hist   <<<1024, 256, 0, stream>>>(dst, counts, E);
    k_scan1  <<<nblk, SCH, 0, stream>>>(counts, partials, N);
    k_scan2  <<<1, 1024, 0, stream>>>(partials, nblk);
    k_scan3  <<<nblk, SCH, 0, stream>>>(counts, partials, offsets, N);
    k_scatter<<<1024, 256, 0, stream>>>(dst, src, offsets, cursor, csr, E);
    k_node   <<<(N + 3) / 4, 256, 0, stream>>>(z_h, dz, offsets, csr, out, N);
}

// Round 11
// 165.677 us; speedup vs baseline: 1.2628x; 1.0823x over previous
//
#include <hip/hip_runtime.h>
#include <hip/hip_fp16.h>
#include <math.h>

#define IN_DIM   128
#define OUT_DIM  128
#define FEAT_DIM 64
#define NB       64     // nodes per k_linear block
#define SCH      256    // scan chunk size == dsts per bucket

__device__ __forceinline__ float2 h2f2(unsigned u) {
    __half2 h = *reinterpret_cast<const __half2*>(&u);
    return __half22float2(h);
}

// ---------------------------------------------------------------------------
// z = fp16(h @ W_fc) ; dz = feat @ W_dst.  256 threads/block, 64 nodes/block.
// Grid = 2*nbz blocks: first nbz do z (fp16 out), rest do dz (fp32 out).
// ---------------------------------------------------------------------------
__global__ __launch_bounds__(256) void k_linear(
        const float* __restrict__ h, const float* __restrict__ feat,
        const float* __restrict__ Wfc, const float* __restrict__ Wdst,
        unsigned short* __restrict__ z_h, float* __restrict__ dz, int N, int nbz) {
    int t  = threadIdx.x;        // 0..255
    int c  = t & 31;             // cols 4c..4c+3
    int j0 = t >> 5;             // 0..7 -> nodes n0 + 8*j0 + jj
    int b  = blockIdx.x;
    bool do_z = (b < nbz);
    int n0 = (do_z ? b : b - nbz) * NB;

    __shared__ float4 s[NB * 32];   // 32 KB

    float4 acc[8];
#pragma unroll
    for (int jj = 0; jj < 8; ++jj) acc[jj] = make_float4(0.f, 0.f, 0.f, 0.f);

    if (do_z) {
        for (int i = t; i < NB * 32; i += 256) {
            int row = i >> 5, col = i & 31;
            int n = min(n0 + row, N - 1);
            s[i] = ((const float4*)(h + (size_t)n * IN_DIM))[col];
        }
        __syncthreads();

        const float4* Wf4 = (const float4*)Wfc;
#pragma unroll 2
        for (int k4 = 0; k4 < IN_DIM / 4; ++k4) {
            float4 w0 = Wf4[(size_t)(4 * k4 + 0) * 32 + c];
            float4 w1 = Wf4[(size_t)(4 * k4 + 1) * 32 + c];
            float4 w2 = Wf4[(size_t)(4 * k4 + 2) * 32 + c];
            float4 w3 = Wf4[(size_t)(4 * k4 + 3) * 32 + c];
#pragma unroll
            for (int jj = 0; jj < 8; ++jj) {
                float4 hv = s[(j0 * 8 + jj) * 32 + k4];
                acc[jj].x += hv.x * w0.x + hv.y * w1.x + hv.z * w2.x + hv.w * w3.x;
                acc[jj].y += hv.x * w0.y + hv.y * w1.y + hv.z * w2.y + hv.w * w3.y;
                acc[jj].z += hv.x * w0.z + hv.y * w1.z + hv.z * w2.z + hv.w * w3.z;
                acc[jj].w += hv.x * w0.w + hv.y * w1.w + hv.z * w2.w + hv.w * w3.w;
            }
        }
#pragma unroll
        for (int jj = 0; jj < 8; ++jj) {
            int n = n0 + j0 * 8 + jj;
            if (n < N) {
                __half2 p0 = __floats2half2_rn(acc[jj].x, acc[jj].y);
                __half2 p1 = __floats2half2_rn(acc[jj].z, acc[jj].w);
                uint2 pk;
                pk.x = *reinterpret_cast<unsigned*>(&p0);
                pk.y = *reinterpret_cast<unsigned*>(&p1);
                ((uint2*)(z_h + (size_t)n * OUT_DIM))[c] = pk;
            }
        }
    } else {
        for (int i = t; i < NB * 16; i += 256) {
            int row = i >> 4, col = i & 15;
            int n = min(n0 + row, N - 1);
            s[i] = ((const float4*)(feat + (size_t)n * FEAT_DIM))[col];
        }
        __syncthreads();

        const float4* Wd4 = (const float4*)Wdst;
#pragma unroll 2
        for (int k4 = 0; k4 < FEAT_DIM / 4; ++k4) {
            float4 w0 = Wd4[(size_t)(4 * k4 + 0) * 32 + c];
            float4 w1 = Wd4[(size_t)(4 * k4 + 1) * 32 + c];
            float4 w2 = Wd4[(size_t)(4 * k4 + 2) * 32 + c];
            float4 w3 = Wd4[(size_t)(4 * k4 + 3) * 32 + c];
#pragma unroll
            for (int jj = 0; jj < 8; ++jj) {
                float4 fv = s[(j0 * 8 + jj) * 16 + k4];
                acc[jj].x += fv.x * w0.x + fv.y * w1.x + fv.z * w2.x + fv.w * w3.x;
                acc[jj].y += fv.x * w0.y + fv.y * w1.y + fv.z * w2.y + fv.w * w3.y;
                acc[jj].z += fv.x * w0.z + fv.y * w1.z + fv.z * w2.z + fv.w * w3.z;
                acc[jj].w += fv.x * w0.w + fv.y * w1.w + fv.z * w2.w + fv.w * w3.w;
            }
        }
#pragma unroll
        for (int jj = 0; jj < 8; ++jj) {
            int n = n0 + j0 * 8 + jj;
            if (n < N) ((float4*)(dz + (size_t)n * OUT_DIM))[c] = acc[jj];
        }
    }
}

// ---------------------------------------------------------------------------
// CSR build: histogram -> scan -> bucketed counting sort (k_bin + k_sort)
// ---------------------------------------------------------------------------
__global__ void k_hist(const int* __restrict__ dst, unsigned* __restrict__ counts, int E) {
    for (int i = blockIdx.x * blockDim.x + threadIdx.x; i < E; i += gridDim.x * blockDim.x)
        atomicAdd(&counts[dst[i]], 1u);
}

__global__ __launch_bounds__(SCH) void k_scan1(const unsigned* __restrict__ counts,
                                               unsigned* __restrict__ partials, int N) {
    int b = blockIdx.x, t = threadIdx.x;
    int idx = b * SCH + t;
    unsigned v = (idx < N) ? counts[idx] : 0u;
#pragma unroll
    for (int off = 32; off; off >>= 1) v += __shfl_xor(v, off);   // wave64 reduce
    __shared__ unsigned sw[SCH / 64];
    if ((t & 63) == 0) sw[t >> 6] = v;
    __syncthreads();
    if (t == 0) {
        unsigned s = 0;
#pragma unroll
        for (int i = 0; i < SCH / 64; ++i) s += sw[i];
        partials[b] = s;
    }
}

__global__ __launch_bounds__(1024) void k_scan2(unsigned* __restrict__ partials, int nblk) {
    __shared__ unsigned s[1024];
    int t = threadIdx.x;
    unsigned v = (t < nblk) ? partials[t] : 0u;
    s[t] = v;
    __syncthreads();
    for (int off = 1; off < 1024; off <<= 1) {
        unsigned u = (t >= off) ? s[t - off] : 0u;
        __syncthreads();
        s[t] += u;
        __syncthreads();
    }
    if (t < nblk) partials[t] = s[t] - v;
}

// also seeds bucket_cursor[b] = offsets[b*256] (bucket == scan chunk)
__global__ __launch_bounds__(SCH) void k_scan3(const unsigned* __restrict__ counts,
                                               const unsigned* __restrict__ partials,
                                               unsigned* __restrict__ offsets,
                                               unsigned* __restrict__ bucket_cursor, int N) {
    int b = blockIdx.x, t = threadIdx.x;
    int idx = b * SCH + t;
    unsigned v = (idx < N) ? counts[idx] : 0u;
    __shared__ unsigned s[SCH];
    s[t] = v;
    __syncthreads();
    for (int off = 1; off < SCH; off <<= 1) {
        unsigned u = (t >= off) ? s[t - off] : 0u;
        __syncthreads();
        s[t] += u;
        __syncthreads();
    }
    unsigned base = partials[b];
    if (idx < N)  offsets[idx] = base + s[t] - v;
    if (idx == N - 1) offsets[N] = base + s[t];
    if (t == 0) bucket_cursor[b] = base;   // == offsets[b*SCH]
}

// stage 1 of counting sort: bin edges by bucket (dst>>8), line-filling writes.
// Each block: LDS histogram over its contiguous edge slice -> one bulk
// reservation per bucket -> grouped (src,dst) writes (~8 edges = 1 line).
__global__ __launch_bounds__(256) void k_bin(
        const int* __restrict__ dst, const int* __restrict__ src,
        unsigned* __restrict__ bucket_cursor, uint2* __restrict__ binned,
        int E, int nbkt) {
    __shared__ unsigned hist[256];
    __shared__ unsigned base[256];
    __shared__ unsigned cur[256];
    int t = threadIdx.x;
    int per = (E + gridDim.x - 1) / gridDim.x;
    int lo = blockIdx.x * per;
    int hi = min(E, lo + per);

    hist[t] = 0;
    cur[t]  = 0;
    __syncthreads();
    for (int i = lo + t; i < hi; i += 256)
        atomicAdd(&hist[dst[i] >> 8], 1u);
    __syncthreads();
    if (t < nbkt) base[t] = atomicAdd(&bucket_cursor[t], hist[t]);
    __syncthreads();
    for (int i = lo + t; i < hi; i += 256) {
        int d = dst[i];
        int bk = d >> 8;
        unsigned slot = base[bk] + atomicAdd(&cur[bk], 1u);
        binned[slot] = make_uint2((unsigned)src[i], (unsigned)d);
    }
}

// stage 2: block b owns dst range [b*256, b*256+256) and the matching csr
// window; LDS per-dst cursors; every csr line written by exactly one block.
__global__ __launch_bounds__(256) void k_sort(
        const uint2* __restrict__ binned, const unsigned* __restrict__ offsets,
        unsigned* __restrict__ csr, int N) {
    __shared__ unsigned off[257];
    __shared__ unsigned cur[256];
    int b = blockIdx.x, t = threadIdx.x;
    int d0 = b << 8;
    int nd = min(N - d0, 256);
    if (t < nd) off[t] = offsets[d0 + t];
    if (t == 0) off[nd] = offsets[d0 + nd];
    cur[t] = 0;
    __syncthreads();
    unsigned lo = off[0], hi = off[nd];
    for (unsigned i = lo + t; i < hi; i += 256) {
        uint2 e = binned[i];
        int ld = (int)(e.y & 255u);
        unsigned pos = off[ld] + atomicAdd(&cur[ld], 1u);
        csr[pos] = e.x;
    }
}

// ---------------------------------------------------------------------------
// Fused attention + aggregation. One 64-lane wave per node (4 nodes/block).
// 16 lanes per edge; z rows gathered in FP16 (256 B/row, one uint4/lane),
// unpacked to fp32 for dot + accumulate. dz stays fp32.
// ---------------------------------------------------------------------------
__global__ __launch_bounds__(256) void k_node(
        const unsigned short* __restrict__ z_h, const float* __restrict__ dz,
        const unsigned* __restrict__ offsets, const unsigned* __restrict__ csr,
        float* __restrict__ out, int N) {
    int lane = threadIdx.x & 63;
    int wv   = threadIdx.x >> 6;          // 0..3
    int g    = lane >> 4;                 // edge slot 0..3
    int l16  = lane & 15;                 // row chunk: dims [8*l16, 8*l16+8)
    int n = blockIdx.x * 4 + wv;
    if (n >= N) return;

    unsigned start = offsets[n];
    int deg = (int)(offsets[n + 1] - start);
    float4* orow = (float4*)(out + (size_t)n * OUT_DIM);
    if (deg == 0) {
        if (g == 0) {
            orow[2 * l16]     = make_float4(0.f, 0.f, 0.f, 0.f);
            orow[2 * l16 + 1] = make_float4(0.f, 0.f, 0.f, 0.f);
        }
        return;
    }

    const float4* dzp = (const float4*)(dz + (size_t)n * OUT_DIM);
    float4 d0 = dzp[2 * l16];
    float4 d1 = dzp[2 * l16 + 1];

    float a[8];
#pragma unroll
    for (int k = 0; k < 8; ++k) a[k] = 0.f;
    float denom = 0.f;

    for (int i = 0; i < deg; i += 8) {
        int eA = i + g;
        int eB = i + 4 + g;
        bool vA = eA < deg;
        bool vB = eB < deg;
        int sA = vA ? (int)csr[start + eA] : 0;
        int sB = vB ? (int)csr[start + eB] : 0;
        uint4 qA = ((const uint4*)(z_h + (size_t)sA * OUT_DIM))[l16];
        uint4 qB = ((const uint4*)(z_h + (size_t)sB * OUT_DIM))[l16];

        float2 zA01 = h2f2(qA.x), zA23 = h2f2(qA.y), zA45 = h2f2(qA.z), zA67 = h2f2(qA.w);
        float2 zB01 = h2f2(qB.x), zB23 = h2f2(qB.y), zB45 = h2f2(qB.z), zB67 = h2f2(qB.w);

        float pA = zA01.x * d0.x + zA01.y * d0.y + zA23.x * d0.z + zA23.y * d0.w
                 + zA45.x * d1.x + zA45.y * d1.y + zA67.x * d1.z + zA67.y * d1.w;
        float pB = zB01.x * d0.x + zB01.y * d0.y + zB23.x * d0.z + zB23.y * d0.w
                 + zB45.x * d1.x + zB45.y * d1.y + zB67.x * d1.z + zB67.y * d1.w;
#pragma unroll
        for (int off = 1; off <= 8; off <<= 1) {   // reduce within 16-lane group
            pA += __shfl_xor(pA, off);
            pB += __shfl_xor(pB, off);
        }
        float wA = vA ? __expf(pA) : 0.f;
        float wB = vB ? __expf(pB) : 0.f;
        denom += wA + wB;
        a[0] += wA * zA01.x + wB * zB01.x;  a[1] += wA * zA01.y + wB * zB01.y;
        a[2] += wA * zA23.x + wB * zB23.x;  a[3] += wA * zA23.y + wB * zB23.y;
        a[4] += wA * zA45.x + wB * zB45.x;  a[5] += wA * zA45.y + wB * zB45.y;
        a[6] += wA * zA67.x + wB * zB67.x;  a[7] += wA * zA67.y + wB * zB67.y;
    }

    // fold the 4 edge-groups together (lanes l, l^16, l^32, l^48)
#pragma unroll
    for (int off = 16; off <= 32; off <<= 1) {
#pragma unroll
        for (int k = 0; k < 8; ++k) a[k] += __shfl_xor(a[k], off);
        denom += __shfl_xor(denom, off);
    }

    if (g == 0) {
        float inv = 1.f / denom;
        orow[2 * l16]     = make_float4(a[0] * inv, a[1] * inv, a[2] * inv, a[3] * inv);
        orow[2 * l16 + 1] = make_float4(a[4] * inv, a[5] * inv, a[6] * inv, a[7] * inv);
    }
}

// ---------------------------------------------------------------------------
extern "C" void kernel_launch(void* const* d_in, const int* in_sizes, int n_in,
                              void* d_out, int out_size, void* d_ws, size_t ws_size,
                              hipStream_t stream) {
    const float* h    = (const float*)d_in[0];
    const float* feat = (const float*)d_in[1];
    const float* Wfc  = (const float*)d_in[2];
    const float* Wdst = (const float*)d_in[3];
    const int*   src  = (const int*)d_in[4];
    const int*   dst  = (const int*)d_in[5];
    float*       out  = (float*)d_out;

    int N = in_sizes[0] / IN_DIM;
    int E = in_sizes[4];

    char* ws = (char*)d_ws;
    unsigned short* z_h = (unsigned short*)ws; ws += (size_t)N * OUT_DIM * sizeof(unsigned short);
    float*    dz       = (float*)ws;    ws += (size_t)N * OUT_DIM * sizeof(float);
    uint2*    binned   = (uint2*)ws;    ws += (size_t)E * sizeof(uint2);
    unsigned* counts   = (unsigned*)ws; ws += (size_t)N * sizeof(unsigned);
    unsigned* offsets  = (unsigned*)ws; ws += (size_t)(N + 1) * sizeof(unsigned);
    unsigned* partials = (unsigned*)ws; ws += (size_t)1024 * sizeof(unsigned);
    unsigned* bcursor  = (unsigned*)ws; ws += (size_t)1024 * sizeof(unsigned);
    unsigned* csr      = (unsigned*)ws;

    int nbz  = (N + NB - 1) / NB;       // 782
    int nblk = (N + SCH - 1) / SCH;     // 196 == bucket count (SCH==256 dsts)

    hipMemsetAsync(counts, 0, (size_t)N * sizeof(unsigned), stream);

    k_linear <<<2 * nbz, 256, 0, stream>>>(h, feat, Wfc, Wdst, z_h, dz, N, nbz);
    k_hist   <<<1024, 256, 0, stream>>>(dst, counts, E);
    k_scan1  <<<nblk, SCH, 0, stream>>>(counts, partials, N);
    k_scan2  <<<1, 1024, 0, stream>>>(partials, nblk);
    k_scan3  <<<nblk, SCH, 0, stream>>>(counts, partials, offsets, bcursor, N);
    k_bin    <<<512, 256, 0, stream>>>(dst, src, bcursor, binned, E, nblk);
    k_sort   <<<nblk, 256, 0, stream>>>(binned, offsets, csr, N);
    k_node   <<<(N + 3) / 4, 256, 0, stream>>>(z_h, dz, offsets, csr, out, N);
}